// Round 1
// 25602.887 us; speedup vs baseline: 2.1960x; 2.1960x over previous
//
#include <hip/hip_runtime.h>
#include <hip/hip_fp16.h>
#include <stdint.h>
#include <stddef.h>

// ---------------------------------------------------------------------------
// LFADS forward on MI355X — round 8: full batch-parallel restructure.
// R0-R7 evidence: identical VALUBusy (24.2/24.4%) across 33ms vs 53ms
// dispatches => clock-state variance (DPM throttle), caused by waves idling
// in cross-block sync. The network is fully batch-parallel => eliminate ALL
// inter-block sync: each block owns batch element(s), keeps state in LDS,
// and streams fp16 weights from L2 (~150 GB/s/CU => gen 7.7us/step,
// enc 3.2us/step). Waves never idle => no throttle, no sync protocol risk.
// ---------------------------------------------------------------------------

#define B_    128
#define T_    1000
#define DIN_  64
#define E_    256
#define F_    64
#define H1_   80
#define DOUT_ 64
#define CLIPV 5.0f
#define LVMIN_ (-9.210340371976182f)
#define TC_   128            // generator time-chunk (ge ring sizing)
#define NCHUNK_ 8

typedef unsigned short u16;
typedef __attribute__((ext_vector_type(8))) unsigned short u16x8;

__device__ __forceinline__ float h2f(u16 u) {
  return __half2float(__builtin_bit_cast(__half, u));
}
__device__ __forceinline__ float sigm_(float x) { return 1.0f/(1.0f + expf(-x)); }

// ------------------------- weight prep --------------------------------------
// Encoder weights per chain, fp16, layout ih: [k8<8][m<3][j<256][i<8]
// followed by hh: [k8<32][m<3][j<256][i<8].  (49152 + 196608 = 245760 halfs)

struct PEncArgs { const float* wih[4]; const float* whh[4]; __half* dst; };

__global__ __launch_bounds__(256) void k_prep_enc(PEncArgs a) {
  const int chain = blockIdx.y;
  const int idx = blockIdx.x*256 + threadIdx.x;     // < 245760
  float v;
  if (idx < 49152) {
    const int i = idx & 7, j = (idx >> 3) & 255;
    const int r = idx >> 11;                        // < 24
    const int m = r % 3, k8 = r / 3;                // k8 < 8
    v = a.wih[chain][((size_t)(m*E_ + j))*DIN_ + k8*8 + i];
  } else {
    const int t = idx - 49152;
    const int i = t & 7, j = (t >> 3) & 255;
    const int r = t >> 11;                          // < 96
    const int m = r % 3, k8 = r / 3;                // k8 < 32
    v = a.whh[chain][((size_t)(m*E_ + j))*E_ + k8*8 + i];
  }
  a.dst[(size_t)chain*245760 + idx] = __float2half(v);
}

// Generator stream weights: [k8<32][m<9][j<256][i<8] fp16.
// m 0..2 = M rows (con_wih[:,512:576]@fac_w) r/z/n; m 3..5 = con_whh r/z/n;
// m 6..8 = gen_whh r/z/n.
__global__ __launch_bounds__(256) void k_prep_gen(const float* __restrict__ conwih,
                                                  const float* __restrict__ conwhh,
                                                  const float* __restrict__ genwhh,
                                                  const float* __restrict__ facw,
                                                  __half* __restrict__ wg) {
  const int idx = blockIdx.x*256 + threadIdx.x;     // < 589824
  const int i = idx & 7, j = (idx >> 3) & 255;
  const int r = idx >> 11;                          // < 288
  const int m = r % 9, k8 = r / 9;                  // k8 < 32
  const int k = k8*8 + i;
  float v;
  if (m < 3) {
    const float* row = conwih + (size_t)(m*E_ + j)*576 + 512;
    float acc = 0.f;
    for (int f = 0; f < 64; ++f) acc += row[f]*facw[(size_t)f*E_ + k];
    v = acc;
  } else if (m < 6) {
    v = conwhh[(size_t)((m-3)*E_ + j)*E_ + k];
  } else {
    v = genwhh[(size_t)((m-6)*E_ + j)*E_ + k];
  }
  wg[idx] = __float2half(v);
}

// W2 = con_wih[:, 0:512] fp16, layout [k8<64][m<3][j<256][i<8]
__global__ __launch_bounds__(256) void k_prep_w2(const float* __restrict__ conwih,
                                                 __half* __restrict__ w2) {
  const int idx = blockIdx.x*256 + threadIdx.x;     // < 393216
  const int i = idx & 7, j = (idx >> 3) & 255;
  const int r = idx >> 11;                          // < 192
  const int m = r % 3, k8 = r / 3;                  // k8 < 64
  w2[idx] = __float2half(conwih[(size_t)(m*E_ + j)*576 + k8*8 + i]);
}

// Per-feature fused biases for the generator: [j][8] f32
__global__ void k_prep_bias(const float* __restrict__ conwih,
                            const float* __restrict__ conbih,
                            const float* __restrict__ conbhh,
                            const float* __restrict__ facb,
                            const float* __restrict__ genbih,
                            const float* __restrict__ genbhh,
                            float* __restrict__ bias8) {
  const int j = threadIdx.x;
  float wfb[3];
  #pragma unroll
  for (int m = 0; m < 3; ++m) {
    const float* row = conwih + (size_t)(m*E_ + j)*576 + 512;
    float s = 0.f;
    for (int f = 0; f < 64; ++f) s += row[f]*facb[f];
    wfb[m] = s;
  }
  float* o = bias8 + j*8;
  o[0] = conbih[j]      + conbhh[j]      + wfb[0];  // con r
  o[1] = conbih[E_+j]   + conbhh[E_+j]   + wfb[1];  // con z
  o[2] = conbih[2*E_+j] + wfb[2];                   // con n (input side)
  o[3] = conbhh[2*E_+j];                            // con n (hidden side)
  o[4] = genbih[j]      + genbhh[j];                // gen r
  o[5] = genbih[E_+j]   + genbhh[E_+j];             // gen z
  o[6] = genbih[2*E_+j];                            // gen n (input side)
  o[7] = genbhh[2*E_+j];                            // gen n (hidden side)
}

// ------------------------- encoder (batch-parallel, sync-free) ---------------

struct EncArgs {
  const float* x;                       // [B][T][64]
  const float* bih[4]; const float* bhh[4];
  const __half* wenc;                   // [4][245760]
  __half* efS; __half* ebS;             // [B][T][256] fp16
  float* hgF; float* hgB;               // [128][256] f32
};

__global__ __launch_bounds__(256) void k_encoder(EncArgs a) {
  __shared__ __align__(16) float sh[2][E_];
  __shared__ __align__(16) float sx[2][DIN_];
  const int chain = blockIdx.x & 3;          // 0=egf 1=ecf 2=egb 3=ecb
  const int pair  = blockIdx.x >> 2;
  const int b0 = pair*2;
  const int j = threadIdx.x;
  const bool bwd = (chain >= 2);
  const __half* Wih = a.wenc + (size_t)chain*245760;
  const __half* Whh = Wih + 49152;
  __half* st = (chain == 1) ? a.efS : (chain == 3 ? a.ebS : nullptr);
  float* hgout = (chain == 0) ? a.hgF : (chain == 2 ? a.hgB : nullptr);

  const float br  = a.bih[chain][j]      + a.bhh[chain][j];
  const float bz  = a.bih[chain][E_+j]   + a.bhh[chain][E_+j];
  const float bni = a.bih[chain][2*E_+j];
  const float bnh = a.bhh[chain][2*E_+j];

  sh[0][j] = 0.f; sh[1][j] = 0.f;
  float lh0 = 0.f, lh1 = 0.f;

  for (int t = 0; t < T_; ++t) {
    const int tt = bwd ? (T_-1-t) : t;
    __syncthreads();                      // order prev sh-writes / sx reuse
    if (j < 128) {
      const int bb = j >> 6, k = j & 63;
      sx[bb][k] = a.x[((size_t)(b0+bb)*T_ + tt)*DIN_ + k];
    }
    __syncthreads();

    float air0=0,air1=0,aiz0=0,aiz1=0,ain0=0,ain1=0;
    float ahr0=0,ahr1=0,ahz0=0,ahz1=0,ahn0=0,ahn1=0;

    {   // input-hidden: 8 k-octets, prefetch-1
      u16x8 wc0 = *(const u16x8*)(Wih + ((size_t)0*E_ + j)*8);
      u16x8 wc1 = *(const u16x8*)(Wih + ((size_t)1*E_ + j)*8);
      u16x8 wc2 = *(const u16x8*)(Wih + ((size_t)2*E_ + j)*8);
      for (int k8 = 0; k8 < 8; ++k8) {
        const int kn = (k8 < 7) ? k8+1 : 7;
        u16x8 wn0 = *(const u16x8*)(Wih + ((size_t)(kn*3+0)*E_ + j)*8);
        u16x8 wn1 = *(const u16x8*)(Wih + ((size_t)(kn*3+1)*E_ + j)*8);
        u16x8 wn2 = *(const u16x8*)(Wih + ((size_t)(kn*3+2)*E_ + j)*8);
        float x0v[8], x1v[8];
        *(float4*)&x0v[0] = *(const float4*)&sx[0][k8*8];
        *(float4*)&x0v[4] = *(const float4*)&sx[0][k8*8+4];
        *(float4*)&x1v[0] = *(const float4*)&sx[1][k8*8];
        *(float4*)&x1v[4] = *(const float4*)&sx[1][k8*8+4];
        #pragma unroll
        for (int i = 0; i < 8; ++i) {
          const float fr = h2f(wc0[i]), fz = h2f(wc1[i]), fn = h2f(wc2[i]);
          air0 += fr*x0v[i]; air1 += fr*x1v[i];
          aiz0 += fz*x0v[i]; aiz1 += fz*x1v[i];
          ain0 += fn*x0v[i]; ain1 += fn*x1v[i];
        }
        wc0 = wn0; wc1 = wn1; wc2 = wn2;
      }
    }
    {   // hidden-hidden: 32 k-octets, prefetch-1
      u16x8 wc0 = *(const u16x8*)(Whh + ((size_t)0*E_ + j)*8);
      u16x8 wc1 = *(const u16x8*)(Whh + ((size_t)1*E_ + j)*8);
      u16x8 wc2 = *(const u16x8*)(Whh + ((size_t)2*E_ + j)*8);
      for (int k8 = 0; k8 < 32; ++k8) {
        const int kn = (k8 < 31) ? k8+1 : 31;
        u16x8 wn0 = *(const u16x8*)(Whh + ((size_t)(kn*3+0)*E_ + j)*8);
        u16x8 wn1 = *(const u16x8*)(Whh + ((size_t)(kn*3+1)*E_ + j)*8);
        u16x8 wn2 = *(const u16x8*)(Whh + ((size_t)(kn*3+2)*E_ + j)*8);
        float h0v[8], h1v[8];
        *(float4*)&h0v[0] = *(const float4*)&sh[0][k8*8];
        *(float4*)&h0v[4] = *(const float4*)&sh[0][k8*8+4];
        *(float4*)&h1v[0] = *(const float4*)&sh[1][k8*8];
        *(float4*)&h1v[4] = *(const float4*)&sh[1][k8*8+4];
        #pragma unroll
        for (int i = 0; i < 8; ++i) {
          const float fr = h2f(wc0[i]), fz = h2f(wc1[i]), fn = h2f(wc2[i]);
          ahr0 += fr*h0v[i]; ahr1 += fr*h1v[i];
          ahz0 += fz*h0v[i]; ahz1 += fz*h1v[i];
          ahn0 += fn*h0v[i]; ahn1 += fn*h1v[i];
        }
        wc0 = wn0; wc1 = wn1; wc2 = wn2;
      }
    }
    const float h0p = sh[0][j], h1p = sh[1][j];
    const float r0 = sigm_(air0 + ahr0 + br);
    const float z0 = sigm_(aiz0 + ahz0 + bz);
    const float n0 = tanhf(ain0 + bni + r0*(ahn0 + bnh));
    const float h0n = fminf((1.f - z0)*n0 + z0*h0p, CLIPV);
    const float r1 = sigm_(air1 + ahr1 + br);
    const float z1 = sigm_(aiz1 + ahz1 + bz);
    const float n1 = tanhf(ain1 + bni + r1*(ahn1 + bnh));
    const float h1n = fminf((1.f - z1)*n1 + z1*h1p, CLIPV);
    __syncthreads();                      // all sh reads done
    sh[0][j] = h0n; sh[1][j] = h1n;
    lh0 = h0n; lh1 = h1n;
    if (st) {
      st[((size_t)b0*T_ + tt)*E_ + j]       = __float2half(h0n);
      st[((size_t)(b0+1)*T_ + tt)*E_ + j]   = __float2half(h1n);
    }
  }
  if (hgout) {
    hgout[(size_t)b0*E_ + j]     = lh0;
    hgout[(size_t)(b0+1)*E_ + j] = lh1;
  }
}

// ------------------------- g0 sample ----------------------------------------

__global__ __launch_bounds__(256) void k_g0(const float* __restrict__ hgF,
                                            const float* __restrict__ hgB,
                                            const float* __restrict__ g0mw,
                                            const float* __restrict__ g0mb,
                                            const float* __restrict__ g0vw,
                                            const float* __restrict__ g0vb,
                                            const float* __restrict__ epsg0,
                                            float* __restrict__ S) {
  __shared__ __align__(16) float sf[E_], sb[E_];
  const int b = blockIdx.x, k = threadIdx.x;
  sf[k] = hgF[(size_t)b*E_ + k];
  sb[k] = hgB[(size_t)b*E_ + k];
  __syncthreads();
  const float* mr = g0mw + (size_t)k*512;
  const float* vr = g0vw + (size_t)k*512;
  float dm = 0.f, dv = 0.f;
  for (int i = 0; i < E_; i += 4) {
    const float4 m4 = *(const float4*)(mr + i);
    const float4 v4 = *(const float4*)(vr + i);
    const float4 h4 = *(const float4*)&sf[i];
    dm += m4.x*h4.x + m4.y*h4.y + m4.z*h4.z + m4.w*h4.w;
    dv += v4.x*h4.x + v4.y*h4.y + v4.z*h4.z + v4.w*h4.w;
  }
  for (int i = 0; i < E_; i += 4) {
    const float4 m4 = *(const float4*)(mr + 256 + i);
    const float4 v4 = *(const float4*)(vr + 256 + i);
    const float4 h4 = *(const float4*)&sb[i];
    dm += m4.x*h4.x + m4.y*h4.y + m4.z*h4.z + m4.w*h4.w;
    dv += v4.x*h4.x + v4.y*h4.y + v4.z*h4.z + v4.w*h4.w;
  }
  const float lv = fmaxf(dv + g0vb[k], LVMIN_);
  const float g  = epsg0[(size_t)b*E_ + k]*expf(0.5f*lv) + dm + g0mb[k];
  S[(size_t)b*512 + k]       = g;    // g0
  S[(size_t)b*512 + 256 + k] = 0.f;  // c0
}

// ------------------------- ge chunk GEMM ------------------------------------
// ge[b][tl][768] = con_wih[:, :512] @ [ef_t ; eb_t]  for t = t0+tl

struct GeArgs { const __half* efS; const __half* ebS; const __half* w2;
                __half* ge; int t0; };

__global__ __launch_bounds__(256) void k_ge(GeArgs a) {
  __shared__ __align__(16) float A[8][512];
  const int tile = blockIdx.x;             // 0..15
  const int b = blockIdx.y;
  const int tl0 = tile*8;
  const int j = threadIdx.x;
  for (int r = 0; r < 16; ++r) {
    const int idx = r*256 + j;
    const int tt = idx >> 9, k = idx & 511;
    const int t = a.t0 + tl0 + tt;
    float v = 0.f;
    if (t < T_) {
      v = (k < 256) ? __half2float(a.efS[((size_t)b*T_ + t)*E_ + k])
                    : __half2float(a.ebS[((size_t)b*T_ + t)*E_ + (k-256)]);
    }
    A[tt][k] = v;
  }
  __syncthreads();
  float acc[3][8];
  #pragma unroll
  for (int m = 0; m < 3; ++m)
    #pragma unroll
    for (int tt = 0; tt < 8; ++tt) acc[m][tt] = 0.f;

  for (int k8 = 0; k8 < 64; ++k8) {
    float av[8][8];
    #pragma unroll
    for (int tt = 0; tt < 8; ++tt) {
      *(float4*)&av[tt][0] = *(const float4*)&A[tt][k8*8];
      *(float4*)&av[tt][4] = *(const float4*)&A[tt][k8*8+4];
    }
    #pragma unroll
    for (int m = 0; m < 3; ++m) {
      const u16x8 w = *(const u16x8*)(a.w2 + ((size_t)(k8*3+m)*E_ + j)*8);
      #pragma unroll
      for (int i = 0; i < 8; ++i) {
        const float wv = h2f(w[i]);
        #pragma unroll
        for (int tt = 0; tt < 8; ++tt) acc[m][tt] += wv*av[tt][i];
      }
    }
  }
  #pragma unroll
  for (int m = 0; m < 3; ++m)
    #pragma unroll
    for (int tt = 0; tt < 8; ++tt) {
      const int tl = tl0 + tt;
      a.ge[((size_t)b*TC_ + tl)*768 + m*E_ + j] = __float2half(acc[m][tt]);
    }
}

// ------------------------- generator (batch-parallel, sync-free) -------------

struct GenArgs {
  const __half* wg;        // [32][9][256][8] fp16
  const __half* ge;        // [B][TC_][768] fp16
  const float* bias8;      // [256][8]
  const float* genwih;     // [768][2]
  const float* umw; const float* umb; const float* uvw; const float* uvb;
  const float* epsu;       // [B][T][2]
  const float* facw; const float* facb;   // [64][256], [64]
  float* S;                // [B][512] state carry (g | c)
  char* fout;              // efS base alias: f32 f[64] at byte (b*T+t)*512
  int t0, tcnt;
};

__global__ __launch_bounds__(256) void k_gen(GenArgs a) {
  __shared__ __align__(16) float sg[E_], sc[E_];
  __shared__ __half sfac[E_*F_];           // [k][d] fp16, 32 KiB
  __shared__ float sred[4][4];
  __shared__ float sfr[4][F_];
  const int b = blockIdx.x;
  const int j = threadIdx.x;
  const int lane = j & 63, w = j >> 6;

  for (int idx = j; idx < E_*F_; idx += 256) {
    const int k = idx >> 6, d = idx & 63;
    sfac[idx] = __float2half(a.facw[(size_t)d*E_ + k]);
  }
  sg[j] = a.S[(size_t)b*512 + j];
  sc[j] = a.S[(size_t)b*512 + 256 + j];

  const float* B8 = a.bias8 + j*8;
  const float b_rc = B8[0], b_zc = B8[1], b_nc = B8[2], b_nhc = B8[3];
  const float b_rg = B8[4], b_zg = B8[5], b_ng = B8[6], b_nhg = B8[7];
  const float gur0 = a.genwih[j*2],          gur1 = a.genwih[j*2+1];
  const float guz0 = a.genwih[(E_+j)*2],     guz1 = a.genwih[(E_+j)*2+1];
  const float gun0 = a.genwih[(2*E_+j)*2],   gun1 = a.genwih[(2*E_+j)*2+1];
  const float uw0 = a.umw[j], uw1 = a.umw[E_+j];
  const float uw2 = a.uvw[j], uw3 = a.uvw[E_+j];
  const float umb0 = a.umb[0], umb1 = a.umb[1];
  const float uvb0 = a.uvb[0], uvb1 = a.uvb[1];
  const float facb_l = a.facb[lane];
  __syncthreads();

  for (int tl = 0; tl < a.tcnt; ++tl) {
    const int t = a.t0 + tl;
    // issue small per-step loads early
    const __half* gep = a.ge + ((size_t)b*TC_ + tl)*768;
    const float ge_r = __half2float(gep[j]);
    const float ge_z = __half2float(gep[E_+j]);
    const float ge_n = __half2float(gep[2*E_+j]);
    const float2 ev = *(const float2*)(a.epsu + ((size_t)b*T_ + t)*2);

    float ar=0, az=0, ani=0, anh=0, gr=0, gz=0, gh=0;
    {
      u16x8 wc[9], wn[9];
      #pragma unroll
      for (int m = 0; m < 9; ++m)
        wc[m] = *(const u16x8*)(a.wg + ((size_t)m*E_ + j)*8);
      for (int k8 = 0; k8 < 32; ++k8) {
        const int kn = (k8 < 31) ? k8+1 : 31;
        #pragma unroll
        for (int m = 0; m < 9; ++m)
          wn[m] = *(const u16x8*)(a.wg + ((size_t)(kn*9 + m)*E_ + j)*8);
        float gv[8], cv[8];
        *(float4*)&gv[0] = *(const float4*)&sg[k8*8];
        *(float4*)&gv[4] = *(const float4*)&sg[k8*8+4];
        *(float4*)&cv[0] = *(const float4*)&sc[k8*8];
        *(float4*)&cv[4] = *(const float4*)&sc[k8*8+4];
        #pragma unroll
        for (int i = 0; i < 8; ++i) {
          ar  += h2f(wc[0][i])*gv[i];
          az  += h2f(wc[1][i])*gv[i];
          ani += h2f(wc[2][i])*gv[i];
          ar  += h2f(wc[3][i])*cv[i];
          az  += h2f(wc[4][i])*cv[i];
          anh += h2f(wc[5][i])*cv[i];
          gr  += h2f(wc[6][i])*gv[i];
          gz  += h2f(wc[7][i])*gv[i];
          gh  += h2f(wc[8][i])*gv[i];
        }
        #pragma unroll
        for (int m = 0; m < 9; ++m) wc[m] = wn[m];
      }
    }
    ar  += ge_r; az += ge_z; ani += ge_n;
    // controller GRU
    const float r = sigm_(ar + b_rc);
    const float z = sigm_(az + b_zc);
    const float n = tanhf(ani + b_nc + r*(anh + b_nhc));
    const float cn = fminf((1.f - z)*n + z*sc[j], CLIPV);
    // u = eps*exp(.5 lv) + mean  (block-wide reduce over fresh c)
    float p0 = uw0*cn, p1 = uw1*cn, p2 = uw2*cn, p3 = uw3*cn;
    #pragma unroll
    for (int s = 32; s; s >>= 1) {
      p0 += __shfl_down(p0, s); p1 += __shfl_down(p1, s);
      p2 += __shfl_down(p2, s); p3 += __shfl_down(p3, s);
    }
    if (lane == 0) { sred[w][0]=p0; sred[w][1]=p1; sred[w][2]=p2; sred[w][3]=p3; }
    __syncthreads();
    const float su0 = sred[0][0]+sred[1][0]+sred[2][0]+sred[3][0] + umb0;
    const float su1 = sred[0][1]+sred[1][1]+sred[2][1]+sred[3][1] + umb1;
    const float lv0 = fmaxf(sred[0][2]+sred[1][2]+sred[2][2]+sred[3][2] + uvb0, LVMIN_);
    const float lv1 = fmaxf(sred[0][3]+sred[1][3]+sred[2][3]+sred[3][3] + uvb1, LVMIN_);
    const float u0 = ev.x*expf(0.5f*lv0) + su0;
    const float u1 = ev.y*expf(0.5f*lv1) + su1;
    // generator GRU
    const float rg = sigm_(gr + gur0*u0 + gur1*u1 + b_rg);
    const float zg = sigm_(gz + guz0*u0 + guz1*u1 + b_zg);
    const float ng = tanhf(gun0*u0 + gun1*u1 + b_ng + rg*(gh + b_nhg));
    const float gn = fminf((1.f - zg)*ng + zg*sg[j], CLIPV);
    sc[j] = cn;
    sg[j] = gn;
    __syncthreads();
    // f_t = fac_w @ g_t + fac_b  (stored for deferred MLP)
    {
      float fp = 0.f;
      for (int kk = 0; kk < 64; ++kk) {
        const int k = w*64 + kk;
        fp += __half2float(sfac[k*64 + lane]) * sg[k];
      }
      sfr[w][lane] = fp;
    }
    __syncthreads();
    if (j < F_) {
      const float fv = sfr[0][j] + sfr[1][j] + sfr[2][j] + sfr[3][j] + facb_l;
      float* fo = (float*)(a.fout + ((size_t)b*T_ + t)*512);
      fo[j] = fv;
    }
    __syncthreads();
  }
  a.S[(size_t)b*512 + j]       = sg[j];
  a.S[(size_t)b*512 + 256 + j] = sc[j];
}

// ------------------------- deferred output MLP -------------------------------

struct MlpArgs { const char* fbase; const float* f1w; const float* f1b;
                 const float* clw; const float* clb; float* out; };

__global__ __launch_bounds__(256) void k_mlp(MlpArgs a) {
  __shared__ float sf1T[64*80];     // [k][d]
  __shared__ float sclT[80*64];     // [kh][o]
  __shared__ float sfv[4][64];
  __shared__ float sh1[4][80];
  const int b = blockIdx.y, t0 = blockIdx.x*8;
  const int j = threadIdx.x, lane = j & 63, w = j >> 6;
  for (int idx = j; idx < 5120; idx += 256) {
    const int k = idx / 80, d = idx % 80;
    sf1T[idx] = a.f1w[(size_t)d*64 + k];
  }
  for (int idx = j; idx < 5120; idx += 256) {
    const int kh = idx >> 6, o = idx & 63;
    sclT[idx] = a.clw[(size_t)o*80 + kh];
  }
  __syncthreads();
  for (int ti = 0; ti < 2; ++ti) {
    const int t = t0 + w*2 + ti;
    const float* fp = (const float*)(a.fbase + ((size_t)b*T_ + t)*512);
    sfv[w][lane] = fp[lane];
    __syncthreads();
    float h1a = a.f1b[lane];
    float h1b = (lane < 16) ? a.f1b[64 + lane] : 0.f;
    for (int k = 0; k < 64; ++k) {
      const float fv = sfv[w][k];
      h1a += sf1T[k*80 + lane]*fv;
      if (lane < 16) h1b += sf1T[k*80 + 64 + lane]*fv;
    }
    sh1[w][lane] = fmaxf(h1a, 0.f);
    if (lane < 16) sh1[w][64 + lane] = fmaxf(h1b, 0.f);
    __syncthreads();
    float o = a.clb[lane];
    for (int kh = 0; kh < H1_; ++kh)
      o += sclT[kh*64 + lane]*sh1[w][kh];
    a.out[((size_t)b*T_ + t)*DOUT_ + lane] = o;
    __syncthreads();
  }
}

// ------------------------- host launcher ------------------------------------

extern "C" void kernel_launch(void* const* d_in, const int* in_sizes, int n_in,
                              void* d_out, int out_size, void* d_ws, size_t ws_size,
                              hipStream_t stream) {
  const float* x      = (const float*)d_in[0];
  const float* eps_g0 = (const float*)d_in[1];
  const float* eps_u  = (const float*)d_in[2];
  const float* egf_wih = (const float*)d_in[3],  *egf_whh = (const float*)d_in[4];
  const float* egf_bih = (const float*)d_in[5],  *egf_bhh = (const float*)d_in[6];
  const float* egb_wih = (const float*)d_in[7],  *egb_whh = (const float*)d_in[8];
  const float* egb_bih = (const float*)d_in[9],  *egb_bhh = (const float*)d_in[10];
  const float* ecf_wih = (const float*)d_in[11], *ecf_whh = (const float*)d_in[12];
  const float* ecf_bih = (const float*)d_in[13], *ecf_bhh = (const float*)d_in[14];
  const float* ecb_wih = (const float*)d_in[15], *ecb_whh = (const float*)d_in[16];
  const float* ecb_bih = (const float*)d_in[17], *ecb_bhh = (const float*)d_in[18];
  const float* con_wih = (const float*)d_in[19], *con_whh = (const float*)d_in[20];
  const float* con_bih = (const float*)d_in[21], *con_bhh = (const float*)d_in[22];
  const float* gen_wih = (const float*)d_in[23], *gen_whh = (const float*)d_in[24];
  const float* gen_bih = (const float*)d_in[25], *gen_bhh = (const float*)d_in[26];
  const float* g0m_w = (const float*)d_in[27], *g0m_b = (const float*)d_in[28];
  const float* g0v_w = (const float*)d_in[29], *g0v_b = (const float*)d_in[30];
  const float* um_w = (const float*)d_in[31], *um_b = (const float*)d_in[32];
  const float* uv_w = (const float*)d_in[33], *uv_b = (const float*)d_in[34];
  const float* fac_w = (const float*)d_in[35], *fac_b = (const float*)d_in[36];
  const float* f1_w = (const float*)d_in[37], *f1_b = (const float*)d_in[38];
  const float* cl_w = (const float*)d_in[39], *cl_b = (const float*)d_in[40];
  float* out = (float*)d_out;
  (void)ws_size; (void)in_sizes; (void)n_in; (void)out_size;

  // Workspace layout (total 160,702,464 B <= proven 167,297,024):
  //   efS  [B][T][256] fp16   65,536,000  (prefix aliased by f32 f[64] after use)
  //   ebS  [B][T][256] fp16   65,536,000
  //   ge   [B][TC][768] fp16  25,165,824  (per-chunk ring)
  //   wenc [4][245760] fp16    1,966,080
  //   wg   [589824] fp16       1,179,648
  //   w2   [393216] fp16         786,432
  //   hgF/hgB [2][128][256]f32   262,144
  //   S    [B][512] f32          262,144
  //   bias8 [256][8] f32           8,192
  char* ws = (char*)d_ws;
  __half* efS  = (__half*)(ws + 0);
  __half* ebS  = (__half*)(ws + 65536000ul);
  __half* geb  = (__half*)(ws + 131072000ul);
  __half* wenc = (__half*)(ws + 156237824ul);
  __half* wg   = (__half*)(ws + 158203904ul);
  __half* w2   = (__half*)(ws + 159383552ul);
  float*  hgF  = (float*)(ws + 160169984ul);
  float*  hgB  = (float*)(ws + 160301056ul);
  float*  S    = (float*)(ws + 160432128ul);
  float*  bias8= (float*)(ws + 160694272ul);

  PEncArgs pe;
  pe.wih[0] = egf_wih; pe.whh[0] = egf_whh;
  pe.wih[1] = ecf_wih; pe.whh[1] = ecf_whh;
  pe.wih[2] = egb_wih; pe.whh[2] = egb_whh;
  pe.wih[3] = ecb_wih; pe.whh[3] = ecb_whh;
  pe.dst = wenc;
  k_prep_enc<<<dim3(960, 4), 256, 0, stream>>>(pe);
  k_prep_gen<<<2304, 256, 0, stream>>>(con_wih, con_whh, gen_whh, fac_w, wg);
  k_prep_w2<<<1536, 256, 0, stream>>>(con_wih, w2);
  k_prep_bias<<<1, 256, 0, stream>>>(con_wih, con_bih, con_bhh, fac_b,
                                     gen_bih, gen_bhh, bias8);

  EncArgs ea;
  ea.x = x;
  ea.bih[0] = egf_bih; ea.bhh[0] = egf_bhh;
  ea.bih[1] = ecf_bih; ea.bhh[1] = ecf_bhh;
  ea.bih[2] = egb_bih; ea.bhh[2] = egb_bhh;
  ea.bih[3] = ecb_bih; ea.bhh[3] = ecb_bhh;
  ea.wenc = wenc; ea.efS = efS; ea.ebS = ebS; ea.hgF = hgF; ea.hgB = hgB;
  k_encoder<<<256, 256, 0, stream>>>(ea);

  k_g0<<<128, 256, 0, stream>>>(hgF, hgB, g0m_w, g0m_b, g0v_w, g0v_b, eps_g0, S);

  for (int c = 0; c < NCHUNK_; ++c) {
    GeArgs ga; ga.efS = efS; ga.ebS = ebS; ga.w2 = w2; ga.ge = geb; ga.t0 = c*TC_;
    k_ge<<<dim3(16, B_), 256, 0, stream>>>(ga);
    GenArgs gn;
    gn.wg = wg; gn.ge = geb; gn.bias8 = bias8; gn.genwih = gen_wih;
    gn.umw = um_w; gn.umb = um_b; gn.uvw = uv_w; gn.uvb = uv_b;
    gn.epsu = eps_u; gn.facw = fac_w; gn.facb = fac_b;
    gn.S = S; gn.fout = (char*)ws;
    gn.t0 = c*TC_;
    gn.tcnt = (T_ - c*TC_ < TC_) ? (T_ - c*TC_) : TC_;
    k_gen<<<B_, 256, 0, stream>>>(gn);
  }

  MlpArgs ma; ma.fbase = (const char*)ws; ma.f1w = f1_w; ma.f1b = f1_b;
  ma.clw = cl_w; ma.clb = cl_b; ma.out = out;
  k_mlp<<<dim3(125, B_), 256, 0, stream>>>(ma);
}